// Round 1
// baseline (561.996 us; speedup 1.0000x reference)
//
#include <hip/hip_runtime.h>

#define N_NODES 50000
#define N_EDGES 800000
#define D 64
#define DHID 100

__device__ __forceinline__ float swishf(float x) {
    return x / (1.0f + __expf(-x));
}

// H = X @ W  (X: [N,64], W: [64,64], H: [N,64]) — 4 rows per 256-thread block
__global__ __launch_bounds__(256) void matmul_xw(const float* __restrict__ X,
                                                 const float* __restrict__ W,
                                                 float* __restrict__ H) {
    __shared__ float sW[D * D];     // 16 KB
    __shared__ float sX[4][D];
    int tid = threadIdx.x;
    for (int i = tid; i < D * D; i += 256) sW[i] = W[i];
    int r = tid >> 6;      // 0..3 (row within block)
    int c = tid & 63;      // 0..63 (output col / lane)
    int row = blockIdx.x * 4 + r;
    sX[r][c] = X[row * D + c];
    __syncthreads();
    float acc = 0.f;
#pragma unroll
    for (int k = 0; k < D; ++k) acc += sX[r][k] * sW[k * D + c];
    H[row * D + c] = acc;
}

// agg[dst] += H[src] * w   — 4 edges per 256-thread block, lane = feature
__global__ __launch_bounds__(256) void scatter_edges(const float* __restrict__ H,
                                                     const int* __restrict__ src,
                                                     const int* __restrict__ dst,
                                                     const float* __restrict__ w,
                                                     float* __restrict__ agg) {
    int e = blockIdx.x * 4 + (threadIdx.x >> 6);
    int f = threadIdx.x & 63;
    int s = src[e];
    int d = dst[e];
    float wv = w[e];
    float v = H[s * D + f] * wv;
    atomicAdd(&agg[d * D + f], v);
}

// A = swish(A + b[col]) elementwise over [N,64]
__global__ __launch_bounds__(256) void bias_swish(float* __restrict__ A,
                                                  const float* __restrict__ b) {
    int i = blockIdx.x * 256 + threadIdx.x;
    if (i < N_NODES * D) {
        float v = A[i] + b[i & 63];
        A[i] = swishf(v);
    }
}

// out[n] = sigmoid( swish(h2[n] @ Wd + bd) @ Wo + bo )  — 1 wave per node
__global__ __launch_bounds__(256) void head_kernel(const float* __restrict__ h2,
                                                   const float* __restrict__ Wd,
                                                   const float* __restrict__ bd,
                                                   const float* __restrict__ Wo,
                                                   const float* __restrict__ bo,
                                                   float* __restrict__ out) {
    __shared__ float sWd[D * DHID];   // 25.6 KB
    __shared__ float sWo[DHID];
    __shared__ float sbd[DHID];
    __shared__ float sRow[4][D];
    int tid = threadIdx.x;
    for (int i = tid; i < D * DHID; i += 256) sWd[i] = Wd[i];
    if (tid < DHID) { sWo[tid] = Wo[tid]; sbd[tid] = bd[tid]; }
    int wave = tid >> 6;
    int lane = tid & 63;
    int node = blockIdx.x * 4 + wave;
    sRow[wave][lane] = h2[node * D + lane];
    __syncthreads();

    float partial = 0.f;
    for (int j = lane; j < DHID; j += 64) {
        float acc = sbd[j];
#pragma unroll
        for (int k = 0; k < D; ++k) acc += sRow[wave][k] * sWd[k * DHID + j];
        partial += swishf(acc) * sWo[j];
    }
    // 64-lane reduction
#pragma unroll
    for (int off = 32; off > 0; off >>= 1)
        partial += __shfl_down(partial, off, 64);
    if (lane == 0) {
        float z = partial + bo[0];
        out[node] = 1.f / (1.f + __expf(-z));
    }
}

extern "C" void kernel_launch(void* const* d_in, const int* in_sizes, int n_in,
                              void* d_out, int out_size, void* d_ws, size_t ws_size,
                              hipStream_t stream) {
    const float* x   = (const float*)d_in[0];
    const int* esrc  = (const int*)d_in[1];
    const int* edst  = (const int*)d_in[2];
    const float* ew  = (const float*)d_in[3];
    const float* W1  = (const float*)d_in[4];
    const float* b1  = (const float*)d_in[5];
    const float* W2  = (const float*)d_in[6];
    const float* b2  = (const float*)d_in[7];
    const float* Wd  = (const float*)d_in[8];
    const float* bd  = (const float*)d_in[9];
    const float* Wo  = (const float*)d_in[10];
    const float* bo  = (const float*)d_in[11];
    float* out = (float*)d_out;

    float* bufH = (float*)d_ws;                    // [N,64] matmul result
    float* bufA = bufH + (size_t)N_NODES * D;      // [N,64] aggregate / activations
    const size_t featBytes = (size_t)N_NODES * D * sizeof(float);

    const int mmBlocks   = N_NODES / 4;   // 12500 (exact)
    const int scBlocks   = N_EDGES / 4;   // 200000 (exact)
    const int ewBlocks   = (N_NODES * D + 255) / 256;
    const int headBlocks = N_NODES / 4;   // 12500 (exact)

    // ---- Layer 1 ----
    matmul_xw<<<mmBlocks, 256, 0, stream>>>(x, W1, bufH);
    hipMemsetAsync(bufA, 0, featBytes, stream);
    scatter_edges<<<scBlocks, 256, 0, stream>>>(bufH, esrc, edst, ew, bufA);
    bias_swish<<<ewBlocks, 256, 0, stream>>>(bufA, b1);

    // ---- Layer 2 ----
    matmul_xw<<<mmBlocks, 256, 0, stream>>>(bufA, W2, bufH);
    hipMemsetAsync(bufA, 0, featBytes, stream);
    scatter_edges<<<scBlocks, 256, 0, stream>>>(bufH, esrc, edst, ew, bufA);
    bias_swish<<<ewBlocks, 256, 0, stream>>>(bufA, b2);

    // ---- Head ----
    head_kernel<<<headBlocks, 256, 0, stream>>>(bufA, Wd, bd, Wo, bo, out);
}

// Round 2
// 529.267 us; speedup vs baseline: 1.0618x; 1.0618x over previous
//
#include <hip/hip_runtime.h>

#define N_NODES 50000
#define N_EDGES 800000
#define D 64
#define DHID 100
#define SCAN_BLOCKS ((N_NODES + 1023) / 1024)   // 49

__device__ __forceinline__ float swishf(float x) { return x / (1.0f + __expf(-x)); }

// ---------------- CSR build (by dst) ----------------
__global__ __launch_bounds__(256) void hist_kernel(const int* __restrict__ dst,
                                                   int* __restrict__ deg) {
    int e = blockIdx.x * 256 + threadIdx.x;
    if (e < N_EDGES) atomicAdd(&deg[dst[e]], 1);
}

// block-local exclusive scan; emits per-block sums
__global__ __launch_bounds__(1024) void scanA(const int* __restrict__ deg,
                                              int* __restrict__ rowptr,
                                              int* __restrict__ blockSums) {
    __shared__ int tile[1024];
    int i = blockIdx.x * 1024 + threadIdx.x;
    int v = (i < N_NODES) ? deg[i] : 0;
    tile[threadIdx.x] = v;
    __syncthreads();
    for (int off = 1; off < 1024; off <<= 1) {
        int t = (threadIdx.x >= (unsigned)off) ? tile[threadIdx.x - off] : 0;
        __syncthreads();
        tile[threadIdx.x] += t;
        __syncthreads();
    }
    if (i < N_NODES) rowptr[i] = tile[threadIdx.x] - v;   // exclusive within block
    if (threadIdx.x == 1023) blockSums[blockIdx.x] = tile[1023];
}

// single-wave scan of the 49 block sums; also writes rowptr[N] = total
__global__ __launch_bounds__(64) void scanB(int* __restrict__ blockSums,
                                            int* __restrict__ rowptr) {
    int lane = threadIdx.x;
    int v = (lane < SCAN_BLOCKS) ? blockSums[lane] : 0;
    int incl = v;
#pragma unroll
    for (int off = 1; off < 64; off <<= 1) {
        int t = __shfl_up(incl, off, 64);
        if (lane >= off) incl += t;
    }
    if (lane < SCAN_BLOCKS) blockSums[lane] = incl - v;   // exclusive
    if (lane == 63) rowptr[N_NODES] = incl;               // grand total
}

__global__ __launch_bounds__(1024) void scanC(int* __restrict__ rowptr,
                                              const int* __restrict__ blockSums) {
    int i = blockIdx.x * 1024 + threadIdx.x;
    if (i < N_NODES) rowptr[i] += blockSums[blockIdx.x];
}

// csr[p] = (src_bits, weight), grouped by dst
__global__ __launch_bounds__(256) void fill_kernel(const int* __restrict__ src,
                                                   const int* __restrict__ dst,
                                                   const float* __restrict__ w,
                                                   const int* __restrict__ rowptr,
                                                   int* __restrict__ cursor,
                                                   float2* __restrict__ csr) {
    int e = blockIdx.x * 256 + threadIdx.x;
    if (e < N_EDGES) {
        int d = dst[e];
        int p = rowptr[d] + atomicAdd(&cursor[d], 1);
        csr[p] = make_float2(__int_as_float(src[e]), w[e]);
    }
}

// ---------------- H1 = X @ W1 ----------------
__global__ __launch_bounds__(512) void matmul_xw(const float* __restrict__ X,
                                                 const float* __restrict__ W,
                                                 float* __restrict__ H) {
    __shared__ float sW[D * D];     // 16 KB
    __shared__ float sX[8][D];
    int tid = threadIdx.x;
    for (int i = tid; i < D * D; i += 512) sW[i] = W[i];
    int r = tid >> 6;
    int c = tid & 63;
    int row = blockIdx.x * 8 + r;
    sX[r][c] = X[row * D + c];
    __syncthreads();
    float acc = 0.f;
#pragma unroll
    for (int k = 0; k < D; ++k) acc = fmaf(sX[r][k], sW[k * D + c], acc);
    H[row * D + c] = acc;
}

// ---------------- layer1 aggregate + swish, fused with H2 = act1 @ W2 ----------------
// one wave per node, lane = feature
__global__ __launch_bounds__(256) void gather_fuse1(const float* __restrict__ H1,
                                                    const int* __restrict__ rowptr,
                                                    const float2* __restrict__ csr,
                                                    const float* __restrict__ b1,
                                                    const float* __restrict__ W2,
                                                    float* __restrict__ H2) {
    __shared__ float sW[D * D];     // 16 KB
    int tid = threadIdx.x;
    for (int i = tid; i < D * D; i += 256) sW[i] = W2[i];
    __syncthreads();
    int wave = tid >> 6;
    int lane = tid & 63;
    int node = blockIdx.x * 4 + wave;
    int beg = rowptr[node], end = rowptr[node + 1];
    float acc = 0.f;
    for (int i = beg; i < end; ++i) {
        float2 e = csr[i];                       // wave-uniform 8B load (broadcast)
        int s = __float_as_int(e.x);
        acc = fmaf(H1[s * D + lane], e.y, acc);  // coalesced 256B gather
    }
    float a = swishf(acc + b1[lane]);
    // h2[lane] = sum_k a(lane k) * W2[k][lane] — cross-lane via shfl broadcast
    float h2 = 0.f;
#pragma unroll
    for (int k = 0; k < D; ++k) {
        float av = __shfl(a, k, 64);
        h2 = fmaf(av, sW[k * D + lane], h2);
    }
    H2[node * D + lane] = h2;
}

// ---------------- layer2 aggregate + swish, fused with MLP head ----------------
__global__ __launch_bounds__(256) void gather_fuse2(const float* __restrict__ H2,
                                                    const int* __restrict__ rowptr,
                                                    const float2* __restrict__ csr,
                                                    const float* __restrict__ b2,
                                                    const float* __restrict__ Wd,
                                                    const float* __restrict__ bd,
                                                    const float* __restrict__ Wo,
                                                    const float* __restrict__ bo,
                                                    float* __restrict__ out) {
    __shared__ float sWd[D * DHID];   // 25.6 KB
    __shared__ float sWo[DHID];
    __shared__ float sbd[DHID];
    int tid = threadIdx.x;
    for (int i = tid; i < D * DHID; i += 256) sWd[i] = Wd[i];
    if (tid < DHID) { sWo[tid] = Wo[tid]; sbd[tid] = bd[tid]; }
    __syncthreads();
    int wave = tid >> 6;
    int lane = tid & 63;
    int node = blockIdx.x * 4 + wave;
    int beg = rowptr[node], end = rowptr[node + 1];
    float acc = 0.f;
    for (int i = beg; i < end; ++i) {
        float2 e = csr[i];
        int s = __float_as_int(e.x);
        acc = fmaf(H2[s * D + lane], e.y, acc);
    }
    float a2 = swishf(acc + b2[lane]);

    // dense(100, swish) then dot with Wo: lane covers j0=lane and j1=lane+64
    int j0 = lane;            // always < 100
    int j1 = lane + 64;       // valid iff lane < 36
    bool has1 = (j1 < DHID);
    float t0 = sbd[j0];
    float t1 = has1 ? sbd[j1] : 0.f;
#pragma unroll
    for (int k = 0; k < D; ++k) {
        float av = __shfl(a2, k, 64);
        t0 = fmaf(av, sWd[k * DHID + j0], t0);
        if (has1) t1 = fmaf(av, sWd[k * DHID + j1], t1);
    }
    float partial = swishf(t0) * sWo[j0];
    if (has1) partial += swishf(t1) * sWo[j1];
#pragma unroll
    for (int off = 32; off > 0; off >>= 1)
        partial += __shfl_down(partial, off, 64);
    if (lane == 0) {
        float z = partial + bo[0];
        out[node] = 1.f / (1.f + __expf(-z));
    }
}

extern "C" void kernel_launch(void* const* d_in, const int* in_sizes, int n_in,
                              void* d_out, int out_size, void* d_ws, size_t ws_size,
                              hipStream_t stream) {
    const float* x   = (const float*)d_in[0];
    const int* esrc  = (const int*)d_in[1];
    const int* edst  = (const int*)d_in[2];
    const float* ew  = (const float*)d_in[3];
    const float* W1  = (const float*)d_in[4];
    const float* b1  = (const float*)d_in[5];
    const float* W2  = (const float*)d_in[6];
    const float* b2  = (const float*)d_in[7];
    const float* Wd  = (const float*)d_in[8];
    const float* bd  = (const float*)d_in[9];
    const float* Wo  = (const float*)d_in[10];
    const float* bo  = (const float*)d_in[11];
    float* out = (float*)d_out;

    // workspace layout
    char* ws = (char*)d_ws;
    float*  H1        = (float*)ws;                     ws += (size_t)N_NODES * D * sizeof(float);
    float*  H2        = (float*)ws;                     ws += (size_t)N_NODES * D * sizeof(float);
    float2* csr       = (float2*)ws;                    ws += (size_t)N_EDGES * sizeof(float2);
    int*    rowptr    = (int*)ws;                       ws += (size_t)(N_NODES + 16) * sizeof(int);
    int*    cursor    = (int*)ws;                       ws += (size_t)N_NODES * sizeof(int);
    int*    blockSums = (int*)ws;

    const int edgeBlocks = (N_EDGES + 255) / 256;   // 3125
    const int nodeBlocks = N_NODES / 4;             // 12500

    // ---- CSR build (deg reused as: counts -> scanned in rowptr; cursor for fill) ----
    int* deg = cursor;  // reuse cursor buffer for histogram, then re-zero for fill
    hipMemsetAsync(deg, 0, N_NODES * sizeof(int), stream);
    hist_kernel<<<edgeBlocks, 256, 0, stream>>>(edst, deg);
    scanA<<<SCAN_BLOCKS, 1024, 0, stream>>>(deg, rowptr, blockSums);
    scanB<<<1, 64, 0, stream>>>(blockSums, rowptr);
    scanC<<<SCAN_BLOCKS, 1024, 0, stream>>>(rowptr, blockSums);
    hipMemsetAsync(cursor, 0, N_NODES * sizeof(int), stream);
    fill_kernel<<<edgeBlocks, 256, 0, stream>>>(esrc, edst, ew, rowptr, cursor, csr);

    // ---- layer 1 matmul ----
    matmul_xw<<<N_NODES / 8, 512, 0, stream>>>(x, W1, H1);

    // ---- layer 1 aggregate + swish + layer 2 matmul (fused) ----
    gather_fuse1<<<nodeBlocks, 256, 0, stream>>>(H1, rowptr, csr, b1, W2, H2);

    // ---- layer 2 aggregate + swish + MLP head (fused) ----
    gather_fuse2<<<nodeBlocks, 256, 0, stream>>>(H2, rowptr, csr, b2, Wd, bd, Wo, bo, out);
}

// Round 3
// 405.515 us; speedup vs baseline: 1.3859x; 1.3052x over previous
//
#include <hip/hip_runtime.h>

#define N_NODES 50000
#define N_EDGES 800000
#define D 64
#define DHID 100
#define SCAN_BLOCKS ((N_NODES + 1023) / 1024)   // 49

__device__ __forceinline__ float swishf(float x) { return x / (1.0f + __expf(-x)); }

// ---------------- CSR build (by dst) ----------------
__global__ __launch_bounds__(256) void hist_kernel(const int* __restrict__ dst,
                                                   int* __restrict__ deg) {
    int e = blockIdx.x * 256 + threadIdx.x;
    if (e < N_EDGES) atomicAdd(&deg[dst[e]], 1);
}

__global__ __launch_bounds__(1024) void scanA(const int* __restrict__ deg,
                                              int* __restrict__ rowptr,
                                              int* __restrict__ blockSums) {
    __shared__ int tile[1024];
    int i = blockIdx.x * 1024 + threadIdx.x;
    int v = (i < N_NODES) ? deg[i] : 0;
    tile[threadIdx.x] = v;
    __syncthreads();
    for (int off = 1; off < 1024; off <<= 1) {
        int t = (threadIdx.x >= (unsigned)off) ? tile[threadIdx.x - off] : 0;
        __syncthreads();
        tile[threadIdx.x] += t;
        __syncthreads();
    }
    if (i < N_NODES) rowptr[i] = tile[threadIdx.x] - v;
    if (threadIdx.x == 1023) blockSums[blockIdx.x] = tile[1023];
}

__global__ __launch_bounds__(64) void scanB(int* __restrict__ blockSums,
                                            int* __restrict__ rowptr) {
    int lane = threadIdx.x;
    int v = (lane < SCAN_BLOCKS) ? blockSums[lane] : 0;
    int incl = v;
#pragma unroll
    for (int off = 1; off < 64; off <<= 1) {
        int t = __shfl_up(incl, off, 64);
        if (lane >= off) incl += t;
    }
    if (lane < SCAN_BLOCKS) blockSums[lane] = incl - v;
    if (lane == 63) rowptr[N_NODES] = incl;
}

__global__ __launch_bounds__(1024) void scanC(int* __restrict__ rowptr,
                                              const int* __restrict__ blockSums) {
    int i = blockIdx.x * 1024 + threadIdx.x;
    if (i < N_NODES) rowptr[i] += blockSums[blockIdx.x];
}

__global__ __launch_bounds__(256) void fill_kernel(const int* __restrict__ src,
                                                   const int* __restrict__ dst,
                                                   const float* __restrict__ w,
                                                   const int* __restrict__ rowptr,
                                                   int* __restrict__ cursor,
                                                   float2* __restrict__ csr) {
    int e = blockIdx.x * 256 + threadIdx.x;
    if (e < N_EDGES) {
        int d = dst[e];
        int p = rowptr[d] + atomicAdd(&cursor[d], 1);
        csr[p] = make_float2(__int_as_float(src[e]), w[e]);
    }
}

// ---------------- H1 = X @ W1 ----------------
__global__ __launch_bounds__(512) void matmul_xw(const float* __restrict__ X,
                                                 const float* __restrict__ W,
                                                 float* __restrict__ H) {
    __shared__ float sW[D * D];
    __shared__ float sX[8][D];
    int tid = threadIdx.x;
    for (int i = tid; i < D * D; i += 512) sW[i] = W[i];
    int r = tid >> 6;
    int c = tid & 63;
    int row = blockIdx.x * 8 + r;
    sX[r][c] = X[row * D + c];
    __syncthreads();
    float acc = 0.f;
#pragma unroll
    for (int k = 0; k < D; ++k) acc = fmaf(sX[r][k], sW[k * D + c], acc);
    H[row * D + c] = acc;
}

// Shared gather body: LDS-staged CSR indices + 4-way unrolled independent loads.
// Returns the aggregated feature for this (node, lane).
__device__ __forceinline__ float gather_node(const float* __restrict__ H,
                                             const float2* __restrict__ csr,
                                             float2* stage,   // this wave's 64-entry LDS buf
                                             int beg, int end, int lane) {
    float a0 = 0.f, a1 = 0.f, a2 = 0.f, a3 = 0.f;
    for (int base = beg; base < end; base += 64) {
        int cnt = min(64, end - base);
        if (lane < cnt) stage[lane] = csr[base + lane];   // coalesced; wave-private, no barrier
        int i = 0;
        for (; i + 4 <= cnt; i += 4) {
            float2 e0 = stage[i + 0];
            float2 e1 = stage[i + 1];
            float2 e2 = stage[i + 2];
            float2 e3 = stage[i + 3];
            const float* p0 = H + (size_t)__float_as_int(e0.x) * D + lane;
            const float* p1 = H + (size_t)__float_as_int(e1.x) * D + lane;
            const float* p2 = H + (size_t)__float_as_int(e2.x) * D + lane;
            const float* p3 = H + (size_t)__float_as_int(e3.x) * D + lane;
            float v0 = *p0, v1 = *p1, v2 = *p2, v3 = *p3;  // 4 loads in flight
            a0 = fmaf(v0, e0.y, a0);
            a1 = fmaf(v1, e1.y, a1);
            a2 = fmaf(v2, e2.y, a2);
            a3 = fmaf(v3, e3.y, a3);
        }
        for (; i < cnt; ++i) {
            float2 e = stage[i];
            a0 = fmaf(H[(size_t)__float_as_int(e.x) * D + lane], e.y, a0);
        }
    }
    return (a0 + a1) + (a2 + a3);
}

// ---------------- layer1 aggregate + swish + H2 = act1 @ W2 ----------------
__global__ __launch_bounds__(256) void gather_fuse1(const float* __restrict__ H1,
                                                    const int* __restrict__ rowptr,
                                                    const float2* __restrict__ csr,
                                                    const float* __restrict__ b1,
                                                    const float* __restrict__ W2,
                                                    float* __restrict__ H2) {
    __shared__ float sW[D * D];        // 16 KB
    __shared__ float2 stage[4][64];    // 2 KB, one 64-entry buf per wave
    int tid = threadIdx.x;
    for (int i = tid; i < D * D; i += 256) sW[i] = W2[i];
    __syncthreads();
    int wave = tid >> 6;
    int lane = tid & 63;
    int node = blockIdx.x * 4 + wave;
    int beg = rowptr[node], end = rowptr[node + 1];
    float acc = gather_node(H1, csr, stage[wave], beg, end, lane);
    float a = swishf(acc + b1[lane]);
    float h2 = 0.f;
#pragma unroll
    for (int k = 0; k < D; ++k) {
        float av = __shfl(a, k, 64);
        h2 = fmaf(av, sW[k * D + lane], h2);
    }
    H2[node * D + lane] = h2;
}

// ---------------- layer2 aggregate + swish + MLP head ----------------
__global__ __launch_bounds__(256) void gather_fuse2(const float* __restrict__ H2,
                                                    const int* __restrict__ rowptr,
                                                    const float2* __restrict__ csr,
                                                    const float* __restrict__ b2,
                                                    const float* __restrict__ Wd,
                                                    const float* __restrict__ bd,
                                                    const float* __restrict__ Wo,
                                                    const float* __restrict__ bo,
                                                    float* __restrict__ out) {
    __shared__ float sWd[D * DHID];    // 25.6 KB
    __shared__ float sWo[DHID];
    __shared__ float sbd[DHID];
    __shared__ float2 stage[4][64];    // 2 KB
    int tid = threadIdx.x;
    for (int i = tid; i < D * DHID; i += 256) sWd[i] = Wd[i];
    if (tid < DHID) { sWo[tid] = Wo[tid]; sbd[tid] = bd[tid]; }
    __syncthreads();
    int wave = tid >> 6;
    int lane = tid & 63;
    int node = blockIdx.x * 4 + wave;
    int beg = rowptr[node], end = rowptr[node + 1];
    float acc = gather_node(H2, csr, stage[wave], beg, end, lane);
    float a2 = swishf(acc + b2[lane]);

    int j0 = lane;
    int j1 = lane + 64;
    bool has1 = (j1 < DHID);
    float t0 = sbd[j0];
    float t1 = has1 ? sbd[j1] : 0.f;
#pragma unroll
    for (int k = 0; k < D; ++k) {
        float av = __shfl(a2, k, 64);
        t0 = fmaf(av, sWd[k * DHID + j0], t0);
        if (has1) t1 = fmaf(av, sWd[k * DHID + j1], t1);
    }
    float partial = swishf(t0) * sWo[j0];
    if (has1) partial += swishf(t1) * sWo[j1];
#pragma unroll
    for (int off = 32; off > 0; off >>= 1)
        partial += __shfl_down(partial, off, 64);
    if (lane == 0) {
        float z = partial + bo[0];
        out[node] = 1.f / (1.f + __expf(-z));
    }
}

extern "C" void kernel_launch(void* const* d_in, const int* in_sizes, int n_in,
                              void* d_out, int out_size, void* d_ws, size_t ws_size,
                              hipStream_t stream) {
    const float* x   = (const float*)d_in[0];
    const int* esrc  = (const int*)d_in[1];
    const int* edst  = (const int*)d_in[2];
    const float* ew  = (const float*)d_in[3];
    const float* W1  = (const float*)d_in[4];
    const float* b1  = (const float*)d_in[5];
    const float* W2  = (const float*)d_in[6];
    const float* b2  = (const float*)d_in[7];
    const float* Wd  = (const float*)d_in[8];
    const float* bd  = (const float*)d_in[9];
    const float* Wo  = (const float*)d_in[10];
    const float* bo  = (const float*)d_in[11];
    float* out = (float*)d_out;

    char* ws = (char*)d_ws;
    float*  H1        = (float*)ws;                     ws += (size_t)N_NODES * D * sizeof(float);
    float*  H2        = (float*)ws;                     ws += (size_t)N_NODES * D * sizeof(float);
    float2* csr       = (float2*)ws;                    ws += (size_t)N_EDGES * sizeof(float2);
    int*    rowptr    = (int*)ws;                       ws += (size_t)(N_NODES + 16) * sizeof(int);
    int*    cursor    = (int*)ws;                       ws += (size_t)N_NODES * sizeof(int);
    int*    blockSums = (int*)ws;

    const int edgeBlocks = (N_EDGES + 255) / 256;   // 3125
    const int nodeBlocks = N_NODES / 4;             // 12500

    int* deg = cursor;
    hipMemsetAsync(deg, 0, N_NODES * sizeof(int), stream);
    hist_kernel<<<edgeBlocks, 256, 0, stream>>>(edst, deg);
    scanA<<<SCAN_BLOCKS, 1024, 0, stream>>>(deg, rowptr, blockSums);
    scanB<<<1, 64, 0, stream>>>(blockSums, rowptr);
    scanC<<<SCAN_BLOCKS, 1024, 0, stream>>>(rowptr, blockSums);
    hipMemsetAsync(cursor, 0, N_NODES * sizeof(int), stream);
    fill_kernel<<<edgeBlocks, 256, 0, stream>>>(esrc, edst, ew, rowptr, cursor, csr);

    matmul_xw<<<N_NODES / 8, 512, 0, stream>>>(x, W1, H1);
    gather_fuse1<<<nodeBlocks, 256, 0, stream>>>(H1, rowptr, csr, b1, W2, H2);
    gather_fuse2<<<nodeBlocks, 256, 0, stream>>>(H2, rowptr, csr, b2, Wd, bd, Wo, bo, out);
}

// Round 4
// 260.621 us; speedup vs baseline: 2.1564x; 1.5560x over previous
//
#include <hip/hip_runtime.h>

#define N_NODES 50000
#define N_EDGES 800000
#define D 64
#define DHID 100
#define SCAN_BLOCKS ((N_NODES + 1023) / 1024)   // 49

__device__ __forceinline__ float swishf(float x) { return x / (1.0f + __expf(-x)); }

__device__ __forceinline__ void fma4(float4& h, float s, const float4& w) {
    h.x = fmaf(s, w.x, h.x);
    h.y = fmaf(s, w.y, h.y);
    h.z = fmaf(s, w.z, h.z);
    h.w = fmaf(s, w.w, h.w);
}

// ---------------- CSR build (by dst) ----------------
__global__ __launch_bounds__(256) void hist_kernel(const int* __restrict__ dst,
                                                   int* __restrict__ deg) {
    int e = blockIdx.x * 256 + threadIdx.x;
    if (e < N_EDGES) atomicAdd(&deg[dst[e]], 1);
}

__global__ __launch_bounds__(1024) void scanA(const int* __restrict__ deg,
                                              int* __restrict__ rowptr,
                                              int* __restrict__ blockSums) {
    __shared__ int tile[1024];
    int i = blockIdx.x * 1024 + threadIdx.x;
    int v = (i < N_NODES) ? deg[i] : 0;
    tile[threadIdx.x] = v;
    __syncthreads();
    for (int off = 1; off < 1024; off <<= 1) {
        int t = (threadIdx.x >= (unsigned)off) ? tile[threadIdx.x - off] : 0;
        __syncthreads();
        tile[threadIdx.x] += t;
        __syncthreads();
    }
    if (i < N_NODES) rowptr[i] = tile[threadIdx.x] - v;
    if (threadIdx.x == 1023) blockSums[blockIdx.x] = tile[1023];
}

__global__ __launch_bounds__(64) void scanB(int* __restrict__ blockSums,
                                            int* __restrict__ rowptr) {
    int lane = threadIdx.x;
    int v = (lane < SCAN_BLOCKS) ? blockSums[lane] : 0;
    int incl = v;
#pragma unroll
    for (int off = 1; off < 64; off <<= 1) {
        int t = __shfl_up(incl, off, 64);
        if (lane >= off) incl += t;
    }
    if (lane < SCAN_BLOCKS) blockSums[lane] = incl - v;
    if (lane == 63) rowptr[N_NODES] = incl;
}

__global__ __launch_bounds__(1024) void scanC(int* __restrict__ rowptr,
                                              const int* __restrict__ blockSums) {
    int i = blockIdx.x * 1024 + threadIdx.x;
    if (i < N_NODES) rowptr[i] += blockSums[blockIdx.x];
}

__global__ __launch_bounds__(256) void fill_kernel(const int* __restrict__ src,
                                                   const int* __restrict__ dst,
                                                   const float* __restrict__ w,
                                                   const int* __restrict__ rowptr,
                                                   int* __restrict__ cursor,
                                                   float2* __restrict__ csr) {
    int e = blockIdx.x * 256 + threadIdx.x;
    if (e < N_EDGES) {
        int d = dst[e];
        int p = rowptr[d] + atomicAdd(&cursor[d], 1);
        csr[p] = make_float2(__int_as_float(src[e]), w[e]);
    }
}

// Gather (float4): 16 lanes per node (fg = feature group of 4), CSR chunk of 16
// staged in wave-private LDS, inner loop 4-way unrolled (4 dwordx4 in flight/lane).
__device__ __forceinline__ float4 gather_node4(const float4* __restrict__ H4,
                                               const float2* __restrict__ csr,
                                               float2* stage,   // this sub-node's 17-entry buf
                                               int beg, int end, int fg) {
    float4 a0 = {0,0,0,0}, a1 = {0,0,0,0}, a2 = {0,0,0,0}, a3 = {0,0,0,0};
    int nch = (end - beg + 15) >> 4;
    const float4* Hf = H4 + fg;
    for (int c = 0; c < nch; ++c) {
        int idx = beg + (c << 4) + fg;
        float2 e = (idx < end) ? csr[idx] : make_float2(0.0f, 0.0f);  // pad: src=0, w=0
        stage[fg] = e;
#pragma unroll
        for (int j = 0; j < 16; j += 4) {
            float2 e0 = stage[j + 0];
            float2 e1 = stage[j + 1];
            float2 e2 = stage[j + 2];
            float2 e3 = stage[j + 3];
            float4 v0 = Hf[(size_t)__float_as_int(e0.x) * 16];
            float4 v1 = Hf[(size_t)__float_as_int(e1.x) * 16];
            float4 v2 = Hf[(size_t)__float_as_int(e2.x) * 16];
            float4 v3 = Hf[(size_t)__float_as_int(e3.x) * 16];
            fma4(a0, e0.y, v0);
            fma4(a1, e1.y, v1);
            fma4(a2, e2.y, v2);
            fma4(a3, e3.y, v3);
        }
    }
    float4 r;
    r.x = (a0.x + a1.x) + (a2.x + a3.x);
    r.y = (a0.y + a1.y) + (a2.y + a3.y);
    r.z = (a0.z + a1.z) + (a2.z + a3.z);
    r.w = (a0.w + a1.w) + (a2.w + a3.w);
    return r;
}

// ---------------- H1 = X @ W1 (float4) ----------------
__global__ __launch_bounds__(256) void matmul_xw(const float4* __restrict__ X4,
                                                 const float4* __restrict__ W4,
                                                 float4* __restrict__ H4) {
    __shared__ __align__(16) float4 sW[D * 16];       // 16 KB, row-major W as float4
    __shared__ __align__(16) float sX[4][4][68];      // padded activations
    int tid = threadIdx.x;
    for (int i = tid; i < D * 16; i += 256) sW[i] = W4[i];
    __syncthreads();
    int w = tid >> 6, lane = tid & 63, sub = lane >> 4, fg = lane & 15;
    int node = blockIdx.x * 16 + w * 4 + sub;
    float4 xv = X4[(size_t)node * 16 + fg];
    *((float4*)&sX[w][sub][fg * 4]) = xv;
    float4 h = {0,0,0,0};
#pragma unroll
    for (int kc = 0; kc < 16; ++kc) {
        float4 av = *((const float4*)&sX[w][sub][kc * 4]);
        fma4(h, av.x, sW[(4 * kc + 0) * 16 + fg]);
        fma4(h, av.y, sW[(4 * kc + 1) * 16 + fg]);
        fma4(h, av.z, sW[(4 * kc + 2) * 16 + fg]);
        fma4(h, av.w, sW[(4 * kc + 3) * 16 + fg]);
    }
    H4[(size_t)node * 16 + fg] = h;
}

// ---------------- layer1 aggregate + swish + H2 = act1 @ W2 ----------------
__global__ __launch_bounds__(256) void gather_fuse1(const float4* __restrict__ H1_4,
                                                    const int* __restrict__ rowptr,
                                                    const float2* __restrict__ csr,
                                                    const float* __restrict__ b1,
                                                    const float4* __restrict__ W2_4,
                                                    float4* __restrict__ H2_4) {
    __shared__ __align__(16) float4 sW[D * 16];       // 16 KB
    __shared__ __align__(16) float2 stage[4][4][17];  // 2.2 KB
    __shared__ __align__(16) float sAct[4][4][68];    // 4.35 KB
    int tid = threadIdx.x;
    for (int i = tid; i < D * 16; i += 256) sW[i] = W2_4[i];
    __syncthreads();
    int w = tid >> 6, lane = tid & 63, sub = lane >> 4, fg = lane & 15;
    int node = blockIdx.x * 16 + w * 4 + sub;
    int beg = rowptr[node], end = rowptr[node + 1];
    float4 acc = gather_node4(H1_4, csr, stage[w][sub], beg, end, fg);
    float4 b4 = ((const float4*)b1)[fg];
    float4 a;
    a.x = swishf(acc.x + b4.x);
    a.y = swishf(acc.y + b4.y);
    a.z = swishf(acc.z + b4.z);
    a.w = swishf(acc.w + b4.w);
    *((float4*)&sAct[w][sub][fg * 4]) = a;
    float4 h = {0,0,0,0};
#pragma unroll
    for (int kc = 0; kc < 16; ++kc) {
        float4 av = *((const float4*)&sAct[w][sub][kc * 4]);
        fma4(h, av.x, sW[(4 * kc + 0) * 16 + fg]);
        fma4(h, av.y, sW[(4 * kc + 1) * 16 + fg]);
        fma4(h, av.z, sW[(4 * kc + 2) * 16 + fg]);
        fma4(h, av.w, sW[(4 * kc + 3) * 16 + fg]);
    }
    H2_4[(size_t)node * 16 + fg] = h;
}

// ---------------- layer2 aggregate + swish + MLP head ----------------
__global__ __launch_bounds__(256) void gather_fuse2(const float4* __restrict__ H2_4,
                                                    const int* __restrict__ rowptr,
                                                    const float2* __restrict__ csr,
                                                    const float* __restrict__ b2,
                                                    const float* __restrict__ Wd,
                                                    const float* __restrict__ bd,
                                                    const float* __restrict__ Wo,
                                                    const float* __restrict__ bo,
                                                    float* __restrict__ out) {
    __shared__ __align__(16) float sWdT[DHID][68];    // transposed Wd, 27.2 KB
    __shared__ __align__(16) float2 stage[4][4][17];
    __shared__ __align__(16) float sAct[4][4][68];
    __shared__ float sWo[DHID];
    __shared__ float sbd[DHID];
    int tid = threadIdx.x;
    for (int i = tid; i < DHID * D; i += 256) {
        int j = i >> 6;          // 0..99
        int k = i & 63;
        sWdT[j][k] = Wd[k * DHID + j];
    }
    if (tid < DHID) { sWo[tid] = Wo[tid]; sbd[tid] = bd[tid]; }
    __syncthreads();
    int w = tid >> 6, lane = tid & 63, sub = lane >> 4, fg = lane & 15;
    int node = blockIdx.x * 16 + w * 4 + sub;
    int beg = rowptr[node], end = rowptr[node + 1];
    float4 acc = gather_node4(H2_4, csr, stage[w][sub], beg, end, fg);
    float4 b4 = ((const float4*)b2)[fg];
    float4 a;
    a.x = swishf(acc.x + b4.x);
    a.y = swishf(acc.y + b4.y);
    a.z = swishf(acc.z + b4.z);
    a.w = swishf(acc.w + b4.w);
    *((float4*)&sAct[w][sub][fg * 4]) = a;

    float t[7];
#pragma unroll
    for (int tt = 0; tt < 7; ++tt) {
        int j = fg + 16 * tt;
        t[tt] = (j < DHID) ? sbd[j] : 0.f;
    }
#pragma unroll
    for (int kc = 0; kc < 16; ++kc) {
        float4 av = *((const float4*)&sAct[w][sub][kc * 4]);
#pragma unroll
        for (int tt = 0; tt < 7; ++tt) {
            int j = fg + 16 * tt;
            if (j < DHID) {
                float4 wv = *((const float4*)&sWdT[j][kc * 4]);
                t[tt] = fmaf(av.x, wv.x, t[tt]);
                t[tt] = fmaf(av.y, wv.y, t[tt]);
                t[tt] = fmaf(av.z, wv.z, t[tt]);
                t[tt] = fmaf(av.w, wv.w, t[tt]);
            }
        }
    }
    float partial = 0.f;
#pragma unroll
    for (int tt = 0; tt < 7; ++tt) {
        int j = fg + 16 * tt;
        if (j < DHID) partial += swishf(t[tt]) * sWo[j];
    }
    // reduce across the 16 lanes of this sub-node
    partial += __shfl_xor(partial, 1, 64);
    partial += __shfl_xor(partial, 2, 64);
    partial += __shfl_xor(partial, 4, 64);
    partial += __shfl_xor(partial, 8, 64);
    if (fg == 0) {
        float z = partial + bo[0];
        out[node] = 1.f / (1.f + __expf(-z));
    }
}

extern "C" void kernel_launch(void* const* d_in, const int* in_sizes, int n_in,
                              void* d_out, int out_size, void* d_ws, size_t ws_size,
                              hipStream_t stream) {
    const float* x   = (const float*)d_in[0];
    const int* esrc  = (const int*)d_in[1];
    const int* edst  = (const int*)d_in[2];
    const float* ew  = (const float*)d_in[3];
    const float* W1  = (const float*)d_in[4];
    const float* b1  = (const float*)d_in[5];
    const float* W2  = (const float*)d_in[6];
    const float* b2  = (const float*)d_in[7];
    const float* Wd  = (const float*)d_in[8];
    const float* bd  = (const float*)d_in[9];
    const float* Wo  = (const float*)d_in[10];
    const float* bo  = (const float*)d_in[11];
    float* out = (float*)d_out;

    char* ws = (char*)d_ws;
    float*  H1        = (float*)ws;                     ws += (size_t)N_NODES * D * sizeof(float);
    float*  H2        = (float*)ws;                     ws += (size_t)N_NODES * D * sizeof(float);
    float2* csr       = (float2*)ws;                    ws += (size_t)N_EDGES * sizeof(float2);
    int*    rowptr    = (int*)ws;                       ws += (size_t)(N_NODES + 16) * sizeof(int);
    int*    cursor    = (int*)ws;                       ws += (size_t)N_NODES * sizeof(int);
    int*    blockSums = (int*)ws;

    const int edgeBlocks = (N_EDGES + 255) / 256;   // 3125
    const int fuseBlocks = N_NODES / 16;            // 3125 (exact)

    int* deg = cursor;
    hipMemsetAsync(deg, 0, N_NODES * sizeof(int), stream);
    hist_kernel<<<edgeBlocks, 256, 0, stream>>>(edst, deg);
    scanA<<<SCAN_BLOCKS, 1024, 0, stream>>>(deg, rowptr, blockSums);
    scanB<<<1, 64, 0, stream>>>(blockSums, rowptr);
    scanC<<<SCAN_BLOCKS, 1024, 0, stream>>>(rowptr, blockSums);
    hipMemsetAsync(cursor, 0, N_NODES * sizeof(int), stream);
    fill_kernel<<<edgeBlocks, 256, 0, stream>>>(esrc, edst, ew, rowptr, cursor, csr);

    matmul_xw<<<fuseBlocks, 256, 0, stream>>>((const float4*)x, (const float4*)W1, (float4*)H1);
    gather_fuse1<<<fuseBlocks, 256, 0, stream>>>((const float4*)H1, rowptr, csr, b1,
                                                 (const float4*)W2, (float4*)H2);
    gather_fuse2<<<fuseBlocks, 256, 0, stream>>>((const float4*)H2, rowptr, csr, b2,
                                                 Wd, bd, Wo, bo, out);
}

// Round 5
// 242.790 us; speedup vs baseline: 2.3147x; 1.0734x over previous
//
#include <hip/hip_runtime.h>

#define N_NODES 50000
#define N_EDGES 800000
#define D 64
#define DHID 100
#define SCAN_BLOCKS ((N_NODES + 1023) / 1024)   // 49

typedef unsigned short ushort;
typedef unsigned int uint;

__device__ __forceinline__ float swishf(float x) { return x / (1.0f + __expf(-x)); }

__device__ __forceinline__ ushort f2bf(float f) {   // RTNE fp32 -> bf16
    uint u = __float_as_uint(f);
    uint r = (u + 0x7fffu + ((u >> 16) & 1u)) >> 16;
    return (ushort)r;
}
__device__ __forceinline__ float bf_lo(uint d) { return __uint_as_float(d << 16); }
__device__ __forceinline__ float bf_hi(uint d) { return __uint_as_float(d & 0xffff0000u); }

__device__ __forceinline__ void fma4(float4& h, float s, const float4& w) {
    h.x = fmaf(s, w.x, h.x);
    h.y = fmaf(s, w.y, h.y);
    h.z = fmaf(s, w.z, h.z);
    h.w = fmaf(s, w.w, h.w);
}

__device__ __forceinline__ void accum8(float* acc, uint4 v, float w) {
    acc[0] = fmaf(w, bf_lo(v.x), acc[0]);
    acc[1] = fmaf(w, bf_hi(v.x), acc[1]);
    acc[2] = fmaf(w, bf_lo(v.y), acc[2]);
    acc[3] = fmaf(w, bf_hi(v.y), acc[3]);
    acc[4] = fmaf(w, bf_lo(v.z), acc[4]);
    acc[5] = fmaf(w, bf_hi(v.z), acc[5]);
    acc[6] = fmaf(w, bf_lo(v.w), acc[6]);
    acc[7] = fmaf(w, bf_hi(v.w), acc[7]);
}

// ---------------- CSR build (by dst), rank recorded during histogram ----------------
__global__ __launch_bounds__(256) void hist_rank(const int* __restrict__ dst,
                                                 int* __restrict__ deg,
                                                 int* __restrict__ rank) {
    int e = blockIdx.x * 256 + threadIdx.x;
    if (e < N_EDGES) rank[e] = atomicAdd(&deg[dst[e]], 1);
}

// block-local exclusive scan of deg -> partial; per-block sums -> blockSums
__global__ __launch_bounds__(1024) void scanA(const int* __restrict__ deg,
                                              int* __restrict__ partial,
                                              int* __restrict__ blockSums) {
    __shared__ int tile[1024];
    int i = blockIdx.x * 1024 + threadIdx.x;
    int v = (i < N_NODES) ? deg[i] : 0;
    tile[threadIdx.x] = v;
    __syncthreads();
    for (int off = 1; off < 1024; off <<= 1) {
        int t = (threadIdx.x >= (unsigned)off) ? tile[threadIdx.x - off] : 0;
        __syncthreads();
        tile[threadIdx.x] += t;
        __syncthreads();
    }
    if (i < N_NODES) partial[i] = tile[threadIdx.x] - v;
    if (threadIdx.x == 1023) blockSums[blockIdx.x] = tile[1023];
}

// exclusive-scan blockSums in place; also partial[N_NODES] = last block's raw sum
// (so that rp(i) = partial[i] + blockSums[i>>10] holds for i == N_NODES too)
__global__ __launch_bounds__(64) void scanB(int* __restrict__ blockSums,
                                            int* __restrict__ partial) {
    int lane = threadIdx.x;
    int v = (lane < SCAN_BLOCKS) ? blockSums[lane] : 0;
    int incl = v;
#pragma unroll
    for (int off = 1; off < 64; off <<= 1) {
        int t = __shfl_up(incl, off, 64);
        if (lane >= off) incl += t;
    }
    if (lane < SCAN_BLOCKS) blockSums[lane] = incl - v;
    if (lane == SCAN_BLOCKS - 1) partial[N_NODES] = v;
}

__global__ __launch_bounds__(256) void fill_kernel(const int* __restrict__ src,
                                                   const int* __restrict__ dst,
                                                   const float* __restrict__ w,
                                                   const int* __restrict__ rank,
                                                   const int* __restrict__ partial,
                                                   const int* __restrict__ blockSums,
                                                   float2* __restrict__ csr) {
    int e = blockIdx.x * 256 + threadIdx.x;
    if (e < N_EDGES) {
        int d = dst[e];
        int p = partial[d] + blockSums[d >> 10] + rank[e];
        csr[p] = make_float2(__int_as_float(src[e]), w[e]);
    }
}

// ---------------- H1 = X @ W1  (fp32 in, bf16 out) ----------------
__global__ __launch_bounds__(256) void matmul_f32(const float4* __restrict__ X4,
                                                  const float4* __restrict__ W4,
                                                  ushort* __restrict__ Hbf) {
    __shared__ __align__(16) float4 sW[D * 16];       // 16 KB
    __shared__ __align__(16) float sX[4][4][68];
    int tid = threadIdx.x;
    for (int i = tid; i < D * 16; i += 256) sW[i] = W4[i];
    __syncthreads();
    int w = tid >> 6, lane = tid & 63, sub = lane >> 4, fg = lane & 15;
    int node = blockIdx.x * 16 + w * 4 + sub;
    float4 xv = X4[(size_t)node * 16 + fg];
    *((float4*)&sX[w][sub][fg * 4]) = xv;
    float4 h = {0, 0, 0, 0};
#pragma unroll
    for (int kc = 0; kc < 16; ++kc) {
        float4 av = *((const float4*)&sX[w][sub][kc * 4]);
        fma4(h, av.x, sW[(4 * kc + 0) * 16 + fg]);
        fma4(h, av.y, sW[(4 * kc + 1) * 16 + fg]);
        fma4(h, av.z, sW[(4 * kc + 2) * 16 + fg]);
        fma4(h, av.w, sW[(4 * kc + 3) * 16 + fg]);
    }
    uint2 u;
    u.x = (uint)f2bf(h.x) | ((uint)f2bf(h.y) << 16);
    u.y = (uint)f2bf(h.z) | ((uint)f2bf(h.w) << 16);
    *((uint2*)(Hbf + ((size_t)node << 6) + (fg << 2))) = u;
}

// ---------------- H2 = act1 @ W2  (bf16 in, bf16 out) ----------------
__global__ __launch_bounds__(256) void matmul_bf(const ushort* __restrict__ Abf,
                                                 const float4* __restrict__ W4,
                                                 ushort* __restrict__ Hbf) {
    __shared__ __align__(16) float4 sW[D * 16];
    __shared__ __align__(16) float sX[4][4][68];
    int tid = threadIdx.x;
    for (int i = tid; i < D * 16; i += 256) sW[i] = W4[i];
    __syncthreads();
    int w = tid >> 6, lane = tid & 63, sub = lane >> 4, fg = lane & 15;
    int node = blockIdx.x * 16 + w * 4 + sub;
    uint2 ua = *((const uint2*)(Abf + ((size_t)node << 6) + (fg << 2)));
    float4 xv = make_float4(bf_lo(ua.x), bf_hi(ua.x), bf_lo(ua.y), bf_hi(ua.y));
    *((float4*)&sX[w][sub][fg * 4]) = xv;
    float4 h = {0, 0, 0, 0};
#pragma unroll
    for (int kc = 0; kc < 16; ++kc) {
        float4 av = *((const float4*)&sX[w][sub][kc * 4]);
        fma4(h, av.x, sW[(4 * kc + 0) * 16 + fg]);
        fma4(h, av.y, sW[(4 * kc + 1) * 16 + fg]);
        fma4(h, av.z, sW[(4 * kc + 2) * 16 + fg]);
        fma4(h, av.w, sW[(4 * kc + 3) * 16 + fg]);
    }
    uint2 u;
    u.x = (uint)f2bf(h.x) | ((uint)f2bf(h.y) << 16);
    u.y = (uint)f2bf(h.z) | ((uint)f2bf(h.w) << 16);
    *((uint2*)(Hbf + ((size_t)node << 6) + (fg << 2))) = u;
}

// ---------------- gather + bias + swish -> bf16 activation ----------------
// one node per wave; lane = edge-slot j (lane>>3) x feature-group fg (lane&7, 8 feats)
__global__ __launch_bounds__(256) void gather_act(const ushort* __restrict__ H,
                                                  const int* __restrict__ partial,
                                                  const int* __restrict__ blockSums,
                                                  const float2* __restrict__ csr,
                                                  const float* __restrict__ bias,
                                                  ushort* __restrict__ actOut) {
    int tid = threadIdx.x;
    int wave = tid >> 6, lane = tid & 63;
    int j = lane >> 3, fg = lane & 7;
    int node = blockIdx.x * 4 + wave;
    int beg = partial[node] + blockSums[node >> 10];
    int np1 = node + 1;
    int end = partial[np1] + blockSums[np1 >> 10];

    float acc[8] = {0, 0, 0, 0, 0, 0, 0, 0};
    int last = end - 1;
    for (int base = beg; base < end; base += 32) {
        int i0 = base + j, i1 = i0 + 8, i2 = i0 + 16, i3 = i0 + 24;
        float2 e0 = csr[min(i0, last)];
        float2 e1 = csr[min(i1, last)];
        float2 e2 = csr[min(i2, last)];
        float2 e3 = csr[min(i3, last)];
        float w0 = (i0 < end) ? e0.y : 0.f;
        float w1 = (i1 < end) ? e1.y : 0.f;
        float w2 = (i2 < end) ? e2.y : 0.f;
        float w3 = (i3 < end) ? e3.y : 0.f;
        uint4 v0 = *((const uint4*)(H + ((size_t)__float_as_int(e0.x) << 6) + (fg << 3)));
        uint4 v1 = *((const uint4*)(H + ((size_t)__float_as_int(e1.x) << 6) + (fg << 3)));
        uint4 v2 = *((const uint4*)(H + ((size_t)__float_as_int(e2.x) << 6) + (fg << 3)));
        uint4 v3 = *((const uint4*)(H + ((size_t)__float_as_int(e3.x) << 6) + (fg << 3)));
        accum8(acc, v0, w0);
        accum8(acc, v1, w1);
        accum8(acc, v2, w2);
        accum8(acc, v3, w3);
    }
    // reduce over the 8 edge slots (lane stride 8)
#pragma unroll
    for (int t = 0; t < 8; ++t) {
        acc[t] += __shfl_xor(acc[t], 8, 64);
        acc[t] += __shfl_xor(acc[t], 16, 64);
        acc[t] += __shfl_xor(acc[t], 32, 64);
    }
    if (j == 0) {
        float4 ba = ((const float4*)bias)[fg * 2];
        float4 bb = ((const float4*)bias)[fg * 2 + 1];
        float r0 = swishf(acc[0] + ba.x);
        float r1 = swishf(acc[1] + ba.y);
        float r2 = swishf(acc[2] + ba.z);
        float r3 = swishf(acc[3] + ba.w);
        float r4 = swishf(acc[4] + bb.x);
        float r5 = swishf(acc[5] + bb.y);
        float r6 = swishf(acc[6] + bb.z);
        float r7 = swishf(acc[7] + bb.w);
        uint4 u;
        u.x = (uint)f2bf(r0) | ((uint)f2bf(r1) << 16);
        u.y = (uint)f2bf(r2) | ((uint)f2bf(r3) << 16);
        u.z = (uint)f2bf(r4) | ((uint)f2bf(r5) << 16);
        u.w = (uint)f2bf(r6) | ((uint)f2bf(r7) << 16);
        *((uint4*)(actOut + ((size_t)node << 6) + (fg << 3))) = u;
    }
}

// ---------------- MLP head: sigmoid(swish(act2 @ Wd + bd) @ Wo + bo) ----------------
__global__ __launch_bounds__(256) void head_kernel(const ushort* __restrict__ act2,
                                                   const float* __restrict__ Wd,
                                                   const float* __restrict__ bd,
                                                   const float* __restrict__ Wo,
                                                   const float* __restrict__ bo,
                                                   float* __restrict__ out) {
    __shared__ __align__(16) float sWdT[DHID][68];    // transposed Wd, 27.2 KB
    __shared__ __align__(16) float sAct[4][4][68];
    __shared__ float sWo[DHID];
    __shared__ float sbd[DHID];
    int tid = threadIdx.x;
    for (int i = tid; i < DHID * D; i += 256) {
        int jj = i >> 6;
        int k = i & 63;
        sWdT[jj][k] = Wd[k * DHID + jj];
    }
    if (tid < DHID) { sWo[tid] = Wo[tid]; sbd[tid] = bd[tid]; }
    __syncthreads();
    int w = tid >> 6, lane = tid & 63, sub = lane >> 4, fg = lane & 15;
    int node = blockIdx.x * 16 + w * 4 + sub;
    uint2 ua = *((const uint2*)(act2 + ((size_t)node << 6) + (fg << 2)));
    float4 a = make_float4(bf_lo(ua.x), bf_hi(ua.x), bf_lo(ua.y), bf_hi(ua.y));
    *((float4*)&sAct[w][sub][fg * 4]) = a;

    float t[7];
#pragma unroll
    for (int tt = 0; tt < 7; ++tt) {
        int jj = fg + 16 * tt;
        t[tt] = (jj < DHID) ? sbd[jj] : 0.f;
    }
#pragma unroll
    for (int kc = 0; kc < 16; ++kc) {
        float4 av = *((const float4*)&sAct[w][sub][kc * 4]);
#pragma unroll
        for (int tt = 0; tt < 7; ++tt) {
            int jj = fg + 16 * tt;
            if (jj < DHID) {
                float4 wv = *((const float4*)&sWdT[jj][kc * 4]);
                t[tt] = fmaf(av.x, wv.x, t[tt]);
                t[tt] = fmaf(av.y, wv.y, t[tt]);
                t[tt] = fmaf(av.z, wv.z, t[tt]);
                t[tt] = fmaf(av.w, wv.w, t[tt]);
            }
        }
    }
    float partialAcc = 0.f;
#pragma unroll
    for (int tt = 0; tt < 7; ++tt) {
        int jj = fg + 16 * tt;
        if (jj < DHID) partialAcc += swishf(t[tt]) * sWo[jj];
    }
    partialAcc += __shfl_xor(partialAcc, 1, 64);
    partialAcc += __shfl_xor(partialAcc, 2, 64);
    partialAcc += __shfl_xor(partialAcc, 4, 64);
    partialAcc += __shfl_xor(partialAcc, 8, 64);
    if (fg == 0) {
        float z = partialAcc + bo[0];
        out[node] = 1.f / (1.f + __expf(-z));
    }
}

extern "C" void kernel_launch(void* const* d_in, const int* in_sizes, int n_in,
                              void* d_out, int out_size, void* d_ws, size_t ws_size,
                              hipStream_t stream) {
    const float* x   = (const float*)d_in[0];
    const int* esrc  = (const int*)d_in[1];
    const int* edst  = (const int*)d_in[2];
    const float* ew  = (const float*)d_in[3];
    const float* W1  = (const float*)d_in[4];
    const float* b1  = (const float*)d_in[5];
    const float* W2  = (const float*)d_in[6];
    const float* b2  = (const float*)d_in[7];
    const float* Wd  = (const float*)d_in[8];
    const float* bd  = (const float*)d_in[9];
    const float* Wo  = (const float*)d_in[10];
    const float* bo  = (const float*)d_in[11];
    float* out = (float*)d_out;

    char* ws = (char*)d_ws;
    ushort* H1   = (ushort*)ws;  ws += (size_t)N_NODES * D * sizeof(ushort);   // 6.4 MB
    ushort* act1 = (ushort*)ws;  ws += (size_t)N_NODES * D * sizeof(ushort);
    ushort* H2   = (ushort*)ws;  ws += (size_t)N_NODES * D * sizeof(ushort);
    ushort* act2 = (ushort*)ws;  ws += (size_t)N_NODES * D * sizeof(ushort);
    float2* csr  = (float2*)ws;  ws += (size_t)N_EDGES * sizeof(float2);       // 6.4 MB
    int* rank    = (int*)ws;     ws += (size_t)N_EDGES * sizeof(int);          // 3.2 MB
    int* partial = (int*)ws;     ws += (size_t)(N_NODES + 16) * sizeof(int);
    int* deg     = (int*)ws;     ws += (size_t)N_NODES * sizeof(int);
    int* blockSums = (int*)ws;

    const int edgeBlocks = (N_EDGES + 255) / 256;   // 3125
    const int mmBlocks   = N_NODES / 16;            // 3125
    const int gBlocks    = N_NODES / 4;             // 12500

    // ---- CSR build ----
    hipMemsetAsync(deg, 0, N_NODES * sizeof(int), stream);
    hist_rank<<<edgeBlocks, 256, 0, stream>>>(edst, deg, rank);
    scanA<<<SCAN_BLOCKS, 1024, 0, stream>>>(deg, partial, blockSums);
    scanB<<<1, 64, 0, stream>>>(blockSums, partial);
    fill_kernel<<<edgeBlocks, 256, 0, stream>>>(esrc, edst, ew, rank, partial, blockSums, csr);

    // ---- layer 1 ----
    matmul_f32<<<mmBlocks, 256, 0, stream>>>((const float4*)x, (const float4*)W1, H1);
    gather_act<<<gBlocks, 256, 0, stream>>>(H1, partial, blockSums, csr, b1, act1);

    // ---- layer 2 ----
    matmul_bf<<<mmBlocks, 256, 0, stream>>>(act1, (const float4*)W2, H2);
    gather_act<<<gBlocks, 256, 0, stream>>>(H2, partial, blockSums, csr, b2, act2);

    // ---- head ----
    head_kernel<<<mmBlocks, 256, 0, stream>>>(act2, Wd, bd, Wo, bo, out);
}

// Round 6
// 220.100 us; speedup vs baseline: 2.5534x; 1.1031x over previous
//
#include <hip/hip_runtime.h>

#define N_NODES 50000
#define N_EDGES 800000
#define D 64
#define DHID 100
#define NTILES (N_NODES / 16)                   // 3125
#define SCAN_BLOCKS ((N_NODES + 1023) / 1024)   // 49

typedef unsigned short ushort;
typedef unsigned int uint;
typedef __attribute__((ext_vector_type(8))) short s16x8;
typedef __attribute__((ext_vector_type(4))) float f32x4;

#define MFMA16(A, B, C) __builtin_amdgcn_mfma_f32_16x16x32_bf16((A), (B), (C), 0, 0, 0)

__device__ __forceinline__ float swishf(float x) { return x / (1.0f + __expf(-x)); }

__device__ __forceinline__ ushort f2bf(float f) {   // RTNE fp32 -> bf16
    uint u = __float_as_uint(f);
    uint r = (u + 0x7fffu + ((u >> 16) & 1u)) >> 16;
    return (ushort)r;
}
__device__ __forceinline__ float bf2f(ushort h) { return __uint_as_float((uint)h << 16); }
__device__ __forceinline__ float bf_lo(uint d) { return __uint_as_float(d << 16); }
__device__ __forceinline__ float bf_hi(uint d) { return __uint_as_float(d & 0xffff0000u); }

__device__ __forceinline__ void accum8(float* acc, uint4 v, float w) {
    acc[0] = fmaf(w, bf_lo(v.x), acc[0]);
    acc[1] = fmaf(w, bf_hi(v.x), acc[1]);
    acc[2] = fmaf(w, bf_lo(v.y), acc[2]);
    acc[3] = fmaf(w, bf_hi(v.y), acc[3]);
    acc[4] = fmaf(w, bf_lo(v.z), acc[4]);
    acc[5] = fmaf(w, bf_hi(v.z), acc[5]);
    acc[6] = fmaf(w, bf_lo(v.w), acc[6]);
    acc[7] = fmaf(w, bf_hi(v.w), acc[7]);
}

// ---------------- CSR build (by dst) ----------------
__global__ __launch_bounds__(256) void hist_rank(const int* __restrict__ dst,
                                                 int* __restrict__ deg,
                                                 int* __restrict__ rank) {
    int e = blockIdx.x * 256 + threadIdx.x;
    if (e < N_EDGES) rank[e] = atomicAdd(&deg[dst[e]], 1);
}

__global__ __launch_bounds__(1024) void scanA(const int* __restrict__ deg,
                                              int* __restrict__ partial,
                                              int* __restrict__ blockSums) {
    __shared__ int tile[1024];
    int i = blockIdx.x * 1024 + threadIdx.x;
    int v = (i < N_NODES) ? deg[i] : 0;
    tile[threadIdx.x] = v;
    __syncthreads();
    for (int off = 1; off < 1024; off <<= 1) {
        int t = (threadIdx.x >= (unsigned)off) ? tile[threadIdx.x - off] : 0;
        __syncthreads();
        tile[threadIdx.x] += t;
        __syncthreads();
    }
    if (i < N_NODES) partial[i] = tile[threadIdx.x] - v;
    if (threadIdx.x == 1023) blockSums[blockIdx.x] = tile[1023];
}

__global__ __launch_bounds__(64) void scanB(int* __restrict__ blockSums,
                                            int* __restrict__ partial) {
    int lane = threadIdx.x;
    int v = (lane < SCAN_BLOCKS) ? blockSums[lane] : 0;
    int incl = v;
#pragma unroll
    for (int off = 1; off < 64; off <<= 1) {
        int t = __shfl_up(incl, off, 64);
        if (lane >= off) incl += t;
    }
    if (lane < SCAN_BLOCKS) blockSums[lane] = incl - v;
    if (lane == SCAN_BLOCKS - 1) partial[N_NODES] = v;
}

__global__ __launch_bounds__(256) void fill_kernel(const int* __restrict__ src,
                                                   const int* __restrict__ dst,
                                                   const float* __restrict__ w,
                                                   const int* __restrict__ rank,
                                                   const int* __restrict__ partial,
                                                   const int* __restrict__ blockSums,
                                                   float2* __restrict__ csr) {
    int e = blockIdx.x * 256 + threadIdx.x;
    if (e < N_EDGES) {
        int d = dst[e];
        int p = partial[d] + blockSums[d >> 10] + rank[e];
        csr[p] = make_float2(__int_as_float(src[e]), w[e]);
    }
}

// ---------------- MFMA layer matmul: H = X @ W, X fp32, W split hi/lo ----------------
// one 16-node tile per wave; W^T staged in LDS as bf16 hi/lo, padded rows (72 shorts)
__global__ __launch_bounds__(256) void mfma_l1(const float* __restrict__ X,
                                               const float* __restrict__ W,
                                               ushort* __restrict__ H) {
    __shared__ __align__(16) short sBT[2][D][72];    // [hi/lo][n][k], 18.4 KB
    __shared__ __align__(16) short rep[4][16][72];   // per-wave C repack, 9.2 KB
    int tid = threadIdx.x;
    for (int idx = tid; idx < D * D; idx += 256) {
        int k = idx >> 6, c = idx & 63;
        float wv = W[idx];
        ushort hi = f2bf(wv);
        ushort lo = f2bf(wv - bf2f(hi));
        sBT[0][c][k] = (short)hi;
        sBT[1][c][k] = (short)lo;
    }
    __syncthreads();
    int w = tid >> 6, lane = tid & 63, quad = lane >> 4, m = lane & 15;
    int tile = blockIdx.x * 4 + w;
    if (tile >= NTILES) return;
    int node0 = tile * 16;

    f32x4 acc[4] = {{0,0,0,0},{0,0,0,0},{0,0,0,0},{0,0,0,0}};
#pragma unroll
    for (int kt = 0; kt < 2; ++kt) {
        int k0 = kt * 32 + quad * 8;
        const float* xp = X + ((size_t)(node0 + m) << 6) + k0;
        float4 xa = *((const float4*)xp);
        float4 xb = *((const float4*)(xp + 4));
        float xv[8] = {xa.x, xa.y, xa.z, xa.w, xb.x, xb.y, xb.z, xb.w};
        s16x8 ahi, alo;
#pragma unroll
        for (int j = 0; j < 8; ++j) {
            ushort hi = f2bf(xv[j]);
            ahi[j] = (short)hi;
            alo[j] = (short)f2bf(xv[j] - bf2f(hi));
        }
#pragma unroll
        for (int ct = 0; ct < 4; ++ct) {
            int n = ct * 16 + m;
            s16x8 bhi = *((const s16x8*)&sBT[0][n][k0]);
            s16x8 blo = *((const s16x8*)&sBT[1][n][k0]);
            acc[ct] = MFMA16(ahi, bhi, acc[ct]);
            acc[ct] = MFMA16(ahi, blo, acc[ct]);
            acc[ct] = MFMA16(alo, bhi, acc[ct]);
        }
    }
    // repack C (col=lane&15, row=quad*4+r) -> row-major bf16, coalesced store
#pragma unroll
    for (int ct = 0; ct < 4; ++ct)
#pragma unroll
        for (int r = 0; r < 4; ++r)
            rep[w][quad * 4 + r][ct * 16 + m] = (short)f2bf(acc[ct][r]);
#pragma unroll
    for (int half = 0; half < 2; ++half) {
        int r = (lane >> 3) + half * 8;
        int c0 = (lane & 7) * 8;
        s16x8 v = *((const s16x8*)&rep[w][r][c0]);
        *((s16x8*)(H + ((size_t)(node0 + r) << 6) + c0)) = v;
    }
}

// ---------------- MFMA layer matmul: H = act @ W, act bf16, W split hi/lo ----------------
__global__ __launch_bounds__(256) void mfma_l2(const ushort* __restrict__ act,
                                               const float* __restrict__ W,
                                               ushort* __restrict__ H) {
    __shared__ __align__(16) short sBT[2][D][72];
    __shared__ __align__(16) short rep[4][16][72];
    int tid = threadIdx.x;
    for (int idx = tid; idx < D * D; idx += 256) {
        int k = idx >> 6, c = idx & 63;
        float wv = W[idx];
        ushort hi = f2bf(wv);
        ushort lo = f2bf(wv - bf2f(hi));
        sBT[0][c][k] = (short)hi;
        sBT[1][c][k] = (short)lo;
    }
    __syncthreads();
    int w = tid >> 6, lane = tid & 63, quad = lane >> 4, m = lane & 15;
    int tile = blockIdx.x * 4 + w;
    if (tile >= NTILES) return;
    int node0 = tile * 16;

    f32x4 acc[4] = {{0,0,0,0},{0,0,0,0},{0,0,0,0},{0,0,0,0}};
#pragma unroll
    for (int kt = 0; kt < 2; ++kt) {
        int k0 = kt * 32 + quad * 8;
        s16x8 a = *((const s16x8*)(act + ((size_t)(node0 + m) << 6) + k0));
#pragma unroll
        for (int ct = 0; ct < 4; ++ct) {
            int n = ct * 16 + m;
            s16x8 bhi = *((const s16x8*)&sBT[0][n][k0]);
            s16x8 blo = *((const s16x8*)&sBT[1][n][k0]);
            acc[ct] = MFMA16(a, bhi, acc[ct]);
            acc[ct] = MFMA16(a, blo, acc[ct]);
        }
    }
#pragma unroll
    for (int ct = 0; ct < 4; ++ct)
#pragma unroll
        for (int r = 0; r < 4; ++r)
            rep[w][quad * 4 + r][ct * 16 + m] = (short)f2bf(acc[ct][r]);
#pragma unroll
    for (int half = 0; half < 2; ++half) {
        int r = (lane >> 3) + half * 8;
        int c0 = (lane & 7) * 8;
        s16x8 v = *((const s16x8*)&rep[w][r][c0]);
        *((s16x8*)(H + ((size_t)(node0 + r) << 6) + c0)) = v;
    }
}

// ---------------- gather + bias + swish -> bf16 activation ----------------
// one node per wave; lane = edge-slot j (lane>>3) x feature-group fg (lane&7, 8 feats)
__global__ __launch_bounds__(256) void gather_act(const ushort* __restrict__ H,
                                                  const int* __restrict__ partial,
                                                  const int* __restrict__ blockSums,
                                                  const float2* __restrict__ csr,
                                                  const float* __restrict__ bias,
                                                  ushort* __restrict__ actOut) {
    int tid = threadIdx.x;
    int wave = tid >> 6, lane = tid & 63;
    int j = lane >> 3, fg = lane & 7;
    int node = blockIdx.x * 4 + wave;
    int beg = partial[node] + blockSums[node >> 10];
    int np1 = node + 1;
    int end = partial[np1] + blockSums[np1 >> 10];

    float acc[8] = {0, 0, 0, 0, 0, 0, 0, 0};
    int last = end - 1;
    for (int base = beg; base < end; base += 32) {
        int i0 = base + j, i1 = i0 + 8, i2 = i0 + 16, i3 = i0 + 24;
        float2 e0 = csr[min(i0, last)];
        float2 e1 = csr[min(i1, last)];
        float2 e2 = csr[min(i2, last)];
        float2 e3 = csr[min(i3, last)];
        float w0 = (i0 < end) ? e0.y : 0.f;
        float w1 = (i1 < end) ? e1.y : 0.f;
        float w2 = (i2 < end) ? e2.y : 0.f;
        float w3 = (i3 < end) ? e3.y : 0.f;
        uint4 v0 = *((const uint4*)(H + ((size_t)__float_as_int(e0.x) << 6) + (fg << 3)));
        uint4 v1 = *((const uint4*)(H + ((size_t)__float_as_int(e1.x) << 6) + (fg << 3)));
        uint4 v2 = *((const uint4*)(H + ((size_t)__float_as_int(e2.x) << 6) + (fg << 3)));
        uint4 v3 = *((const uint4*)(H + ((size_t)__float_as_int(e3.x) << 6) + (fg << 3)));
        accum8(acc, v0, w0);
        accum8(acc, v1, w1);
        accum8(acc, v2, w2);
        accum8(acc, v3, w3);
    }
#pragma unroll
    for (int t = 0; t < 8; ++t) {
        acc[t] += __shfl_xor(acc[t], 8, 64);
        acc[t] += __shfl_xor(acc[t], 16, 64);
        acc[t] += __shfl_xor(acc[t], 32, 64);
    }
    if (j == 0) {
        float4 ba = ((const float4*)bias)[fg * 2];
        float4 bb = ((const float4*)bias)[fg * 2 + 1];
        float r0 = swishf(acc[0] + ba.x);
        float r1 = swishf(acc[1] + ba.y);
        float r2 = swishf(acc[2] + ba.z);
        float r3 = swishf(acc[3] + ba.w);
        float r4 = swishf(acc[4] + bb.x);
        float r5 = swishf(acc[5] + bb.y);
        float r6 = swishf(acc[6] + bb.z);
        float r7 = swishf(acc[7] + bb.w);
        uint4 u;
        u.x = (uint)f2bf(r0) | ((uint)f2bf(r1) << 16);
        u.y = (uint)f2bf(r2) | ((uint)f2bf(r3) << 16);
        u.z = (uint)f2bf(r4) | ((uint)f2bf(r5) << 16);
        u.w = (uint)f2bf(r6) | ((uint)f2bf(r7) << 16);
        *((uint4*)(actOut + ((size_t)node << 6) + (fg << 3))) = u;
    }
}

// ---------------- MFMA head: sigmoid(swish(act2 @ Wd + bd) @ Wo + bo) ----------------
// Wd 64x100 padded to 112 cols (pad bd=0, Wo=0 so pads contribute 0)
#define NCT 7
__global__ __launch_bounds__(256) void mfma_head(const ushort* __restrict__ act2,
                                                 const float* __restrict__ Wd,
                                                 const float* __restrict__ bd,
                                                 const float* __restrict__ Wo,
                                                 const float* __restrict__ bo,
                                                 float* __restrict__ out) {
    __shared__ __align__(16) short sBT[2][NCT * 16][72];   // 32.3 KB
    __shared__ float sbd[NCT * 16];
    __shared__ float sWo[NCT * 16];
    int tid = threadIdx.x;
    for (int idx = tid; idx < NCT * 16 * D; idx += 256) {
        int jj = idx >> 6, k = idx & 63;
        float wv = (jj < DHID) ? Wd[k * DHID + jj] : 0.f;
        ushort hi = f2bf(wv);
        ushort lo = f2bf(wv - bf2f(hi));
        sBT[0][jj][k] = (short)hi;
        sBT[1][jj][k] = (short)lo;
    }
    if (tid < NCT * 16) {
        sbd[tid] = (tid < DHID) ? bd[tid] : 0.f;
        sWo[tid] = (tid < DHID) ? Wo[tid] : 0.f;
    }
    __syncthreads();
    int w = tid >> 6, lane = tid & 63, quad = lane >> 4, m = lane & 15;
    int tile = blockIdx.x * 4 + w;
    if (tile >= NTILES) return;
    int node0 = tile * 16;

    f32x4 acc[NCT];
#pragma unroll
    for (int ct = 0; ct < NCT; ++ct) acc[ct] = (f32x4){0, 0, 0, 0};
#pragma unroll
    for (int kt = 0; kt < 2; ++kt) {
        int k0 = kt * 32 + quad * 8;
        s16x8 a = *((const s16x8*)(act2 + ((size_t)(node0 + m) << 6) + k0));
#pragma unroll
        for (int ct = 0; ct < NCT; ++ct) {
            int n = ct * 16 + m;
            s16x8 bhi = *((const s16x8*)&sBT[0][n][k0]);
            s16x8 blo = *((const s16x8*)&sBT[1][n][k0]);
            acc[ct] = MFMA16(a, bhi, acc[ct]);
            acc[ct] = MFMA16(a, blo, acc[ct]);
        }
    }
    // epilogue: partial[r] = sum over this lane's cols of swish(C + bd)*Wo
    float part[4] = {0, 0, 0, 0};
#pragma unroll
    for (int ct = 0; ct < NCT; ++ct) {
        int jj = ct * 16 + m;
        float bdv = sbd[jj], wov = sWo[jj];
#pragma unroll
        for (int r = 0; r < 4; ++r)
            part[r] = fmaf(swishf(acc[ct][r] + bdv), wov, part[r]);
    }
#pragma unroll
    for (int r = 0; r < 4; ++r) {
        part[r] += __shfl_xor(part[r], 1, 64);
        part[r] += __shfl_xor(part[r], 2, 64);
        part[r] += __shfl_xor(part[r], 4, 64);
        part[r] += __shfl_xor(part[r], 8, 64);
    }
    if (m == 0) {
        float b0 = bo[0];
        float4 o;
        o.x = 1.f / (1.f + __expf(-(part[0] + b0)));
        o.y = 1.f / (1.f + __expf(-(part[1] + b0)));
        o.z = 1.f / (1.f + __expf(-(part[2] + b0)));
        o.w = 1.f / (1.f + __expf(-(part[3] + b0)));
        *((float4*)(out + node0 + quad * 4)) = o;
    }
}

extern "C" void kernel_launch(void* const* d_in, const int* in_sizes, int n_in,
                              void* d_out, int out_size, void* d_ws, size_t ws_size,
                              hipStream_t stream) {
    const float* x   = (const float*)d_in[0];
    const int* esrc  = (const int*)d_in[1];
    const int* edst  = (const int*)d_in[2];
    const float* ew  = (const float*)d_in[3];
    const float* W1  = (const float*)d_in[4];
    const float* b1  = (const float*)d_in[5];
    const float* W2  = (const float*)d_in[6];
    const float* b2  = (const float*)d_in[7];
    const float* Wd  = (const float*)d_in[8];
    const float* bd  = (const float*)d_in[9];
    const float* Wo  = (const float*)d_in[10];
    const float* bo  = (const float*)d_in[11];
    float* out = (float*)d_out;

    char* ws = (char*)d_ws;
    ushort* H1   = (ushort*)ws;  ws += (size_t)N_NODES * D * sizeof(ushort);
    ushort* act1 = (ushort*)ws;  ws += (size_t)N_NODES * D * sizeof(ushort);
    ushort* H2   = (ushort*)ws;  ws += (size_t)N_NODES * D * sizeof(ushort);
    ushort* act2 = (ushort*)ws;  ws += (size_t)N_NODES * D * sizeof(ushort);
    float2* csr  = (float2*)ws;  ws += (size_t)N_EDGES * sizeof(float2);
    int* rank    = (int*)ws;     ws += (size_t)N_EDGES * sizeof(int);
    int* partial = (int*)ws;     ws += (size_t)(N_NODES + 16) * sizeof(int);
    int* deg     = (int*)ws;     ws += (size_t)N_NODES * sizeof(int);
    int* blockSums = (int*)ws;

    const int edgeBlocks = (N_EDGES + 255) / 256;   // 3125
    const int mmBlocks   = (NTILES + 3) / 4;        // 782
    const int gBlocks    = N_NODES / 4;             // 12500

    // ---- CSR build ----
    hipMemsetAsync(deg, 0, N_NODES * sizeof(int), stream);
    hist_rank<<<edgeBlocks, 256, 0, stream>>>(edst, deg, rank);
    scanA<<<SCAN_BLOCKS, 1024, 0, stream>>>(deg, partial, blockSums);
    scanB<<<1, 64, 0, stream>>>(blockSums, partial);
    fill_kernel<<<edgeBlocks, 256, 0, stream>>>(esrc, edst, ew, rank, partial, blockSums, csr);

    // ---- layer 1 ----
    mfma_l1<<<mmBlocks, 256, 0, stream>>>(x, W1, H1);
    gather_act<<<gBlocks, 256, 0, stream>>>(H1, partial, blockSums, csr, b1, act1);

    // ---- layer 2 ----
    mfma_l2<<<mmBlocks, 256, 0, stream>>>(act1, W2, H2);
    gather_act<<<gBlocks, 256, 0, stream>>>(H2, partial, blockSums, csr, b2, act2);

    // ---- head ----
    mfma_head<<<mmBlocks, 256, 0, stream>>>(act2, Wd, bd, Wo, bo, out);
}